// Round 2
// baseline (364.293 us; speedup 1.0000x reference)
//
#include <hip/hip_runtime.h>
#include <stdint.h>

typedef __bf16 bf16x8 __attribute__((ext_vector_type(8)));
typedef float f32x4 __attribute__((ext_vector_type(4)));

static constexpr float QK_SCALE = 0.044194173824159216f; // 1/sqrt(512)

__device__ __forceinline__ uint16_t f2bf(float f) {
    uint32_t x = __builtin_bit_cast(uint32_t, f);
    x += 0x7FFFu + ((x >> 16) & 1u);     // round-to-nearest-even; inputs finite
    return (uint16_t)(x >> 16);
}

// async 16B global->LDS copy (global_load_lds_dwordx4). LDS dest is
// wave-uniform base + lane*16; lds ptr = region_base + lane*16 matches.
__device__ __forceinline__ void cp16(const uint16_t* g, uint16_t* l) {
    __builtin_amdgcn_global_load_lds(
        (__attribute__((address_space(1))) void*)(uint16_t*)g,
        (__attribute__((address_space(3))) void*)l,
        16, 0, 0);
}

// ---------------------------------------------------------------------------
// NT GEMM: C[M,N] = A[M,K] * B[N,K]^T  (both operands K-contiguous, bf16)
// 128x128 block tile, BK=32, 128 threads = 2 waves, each wave owns 128x64.
// LDS: A[128x32] | B[128x32], 16B chunks XOR-swizzled: row r's k-group cg is
// stored at slot column cg ^ ((r>>1)&3)  -> conflict-free ds_read_b128.
// wave0 stages A (8 cp16), wave1 stages B (8 cp16).
// MODE 0: bf16 out, batched (blockIdx.z), scale, no bias
// MODE 2: f32 out + bias0 (final projection)
// MODE 3: QKV split epilogue: n<512 -> Q, <1024 -> K, else V transposed
// ---------------------------------------------------------------------------
template <int MODE>
__global__ __launch_bounds__(128, 2) void gemm_nt(
    const uint16_t* __restrict__ A, const uint16_t* __restrict__ Bm,
    void* __restrict__ C0, void* __restrict__ C1, void* __restrict__ C2,
    const float* __restrict__ bias0, const float* __restrict__ bias1,
    const float* __restrict__ bias2,
    float scale, int K, int ldc, long bsA, long bsB, long bsC)
{
    __shared__ __align__(16) uint16_t SH[8192];   // A: slots 0..511, B: 512..1023

    const int t  = threadIdx.x;
    const int bn = blockIdx.x, bm = blockIdx.y, bz = blockIdx.z;
    const int wave = t >> 6, lane = t & 63;
    const int lm = lane & 15, lq = lane >> 4;
    const int sw = lq ^ ((lm >> 1) & 3);          // read-side swizzled k-group

    const uint16_t* Ab = A  + (long)bz * bsA + (long)bm * 128 * K;
    const uint16_t* Bb = Bm + (long)bz * bsB + (long)bn * 128 * K;
    const uint16_t* gbase = wave ? Bb : Ab;       // wave0 stages A, wave1 B

    // staging plan: instr j covers slots s = wave*512 + j*64 + lane
    int goff[8]; int loff[8];
#pragma unroll
    for (int j = 0; j < 8; ++j) {
        const int s  = j * 64 + lane;             // 0..511 within region
        const int r  = s >> 2;                    // tile row 0..127
        const int cs = s & 3;                     // slot column
        const int cg = cs ^ ((r >> 1) & 3);       // global k-group to fetch
        goff[j] = r * K + cg * 8;
        loff[j] = (wave * 512 + s) * 8;
    }

    f32x4 acc[8][4] = {};

    for (int k0 = 0; k0 < K; k0 += 32) {
#pragma unroll
        for (int j = 0; j < 8; ++j)
            cp16(gbase + goff[j] + k0, SH + loff[j]);
        asm volatile("s_waitcnt vmcnt(0)" ::: "memory");
        __syncthreads();

        bf16x8 af[8], bfr[4];
#pragma unroll
        for (int i = 0; i < 8; ++i)               // A rows i*16+lm, k-grp lq
            af[i] = *(const bf16x8*)&SH[((i * 16 + lm) * 4 + sw) * 8];
#pragma unroll
        for (int j = 0; j < 4; ++j)               // B cols wave*64+j*16+lm
            bfr[j] = *(const bf16x8*)&SH[(512 + (wave * 64 + j * 16 + lm) * 4 + sw) * 8];
#pragma unroll
        for (int i = 0; i < 8; ++i)
#pragma unroll
            for (int j = 0; j < 4; ++j)
                acc[i][j] = __builtin_amdgcn_mfma_f32_16x16x32_bf16(
                    af[i], bfr[j], acc[i][j], 0, 0, 0);
        __syncthreads();
    }

    // epilogue: C/D layout (m89/m91): m = lq*4 + reg (+i*16), n = lm (+j*16)
    const int mbase = bm * 128 + lq * 4;
    const int nbase = bn * 128 + wave * 64 + lm;
#pragma unroll
    for (int i = 0; i < 8; ++i) {
#pragma unroll
        for (int j = 0; j < 4; ++j) {
            const int n = nbase + j * 16;
#pragma unroll
            for (int r = 0; r < 4; ++r) {
                const int m = mbase + i * 16 + r;
                const float v = acc[i][j][r] * scale;
                if (MODE == 0) {
                    ((uint16_t*)C0)[(long)bz * bsC + (long)m * ldc + n] = f2bf(v);
                } else if (MODE == 2) {
                    ((float*)C0)[(long)m * ldc + n] = v + bias0[n];
                } else { // MODE 3: QKV split (wave-uniform branch: 64 | 512)
                    const int sec = n >> 9;
                    const int nn  = n & 511;
                    if (sec == 0) {
                        ((uint16_t*)C0)[(long)m * 512 + nn] = f2bf(v + bias0[nn]);
                    } else if (sec == 1) {
                        ((uint16_t*)C1)[(long)m * 512 + nn] = f2bf(v + bias1[nn]);
                    } else { // V stored transposed per batch: Vt[b][d][s]
                        const int bb = m >> 11, ss = m & 2047;
                        ((uint16_t*)C2)[((long)bb * 512 + nn) * 2048 + ss] =
                            f2bf(v + bias2[nn]);
                    }
                }
            }
        }
    }
}

// x + pos_table -> bf16, 8 elems/thread, exact grid (4096 blocks)
__global__ __launch_bounds__(256) void prep_x(const float* __restrict__ x,
                                              const float* __restrict__ pos,
                                              uint16_t* __restrict__ xb)
{
    const long i8 = ((long)blockIdx.x * 256 + threadIdx.x) * 8;
    const long p8 = i8 & ((1l << 20) - 1);   // S*D = 2^20
    const float4* xv = (const float4*)(x + i8);
    const float4* pv = (const float4*)(pos + p8);
    const float4 a0 = xv[0], a1 = xv[1];
    const float4 b0 = pv[0], b1 = pv[1];
    uint16_t o[8];
    o[0] = f2bf(a0.x + b0.x); o[1] = f2bf(a0.y + b0.y);
    o[2] = f2bf(a0.z + b0.z); o[3] = f2bf(a0.w + b0.w);
    o[4] = f2bf(a1.x + b1.x); o[5] = f2bf(a1.y + b1.y);
    o[6] = f2bf(a1.z + b1.z); o[7] = f2bf(a1.w + b1.w);
    *(uint4*)(xb + i8) = *(uint4*)o;
}

// Wq,Wk,Wv -> stacked wqkv[1536,512] bf16; Wd -> wd bf16. 512 blocks exact.
__global__ __launch_bounds__(256) void prep_w(
    const float* __restrict__ Wq, const float* __restrict__ Wk,
    const float* __restrict__ Wv, const float* __restrict__ Wd,
    uint16_t* __restrict__ wqkv, uint16_t* __restrict__ wd)
{
    const long f = ((long)blockIdx.x * 256 + threadIdx.x) * 8;
    const int  w = (int)(f >> 18);          // 262144 elems per weight
    const long off = f & 262143;
    const float* src = (w == 0) ? Wq : (w == 1) ? Wk : (w == 2) ? Wv : Wd;
    uint16_t* dst = (w < 3) ? (wqkv + (long)w * 262144 + off) : (wd + off);
    const float4* s4 = (const float4*)(src + off);
    const float4 a = s4[0], b = s4[1];
    uint16_t o[8];
    o[0] = f2bf(a.x); o[1] = f2bf(a.y); o[2] = f2bf(a.z); o[3] = f2bf(a.w);
    o[4] = f2bf(b.x); o[5] = f2bf(b.y); o[6] = f2bf(b.z); o[7] = f2bf(b.w);
    *(uint4*)dst = *(uint4*)o;
}

// in-place row softmax over bf16 P rows of length 2048; 1 block (256 thr)/row
__global__ __launch_bounds__(256) void softmax_rows(uint16_t* __restrict__ P)
{
    uint16_t* p = P + (long)blockIdx.x * 2048;
    const int t = threadIdx.x;
    const int lane = t & 63, wave = t >> 6;

    uint4 raw = *(const uint4*)(p + t * 8);
    uint32_t u[4] = {raw.x, raw.y, raw.z, raw.w};
    float x[8];
#pragma unroll
    for (int i = 0; i < 4; ++i) {
        x[2 * i]     = __builtin_bit_cast(float, u[i] << 16);
        x[2 * i + 1] = __builtin_bit_cast(float, u[i] & 0xFFFF0000u);
    }
    float mx = x[0];
#pragma unroll
    for (int i = 1; i < 8; ++i) mx = fmaxf(mx, x[i]);
#pragma unroll
    for (int off = 32; off; off >>= 1) mx = fmaxf(mx, __shfl_xor(mx, off));
    __shared__ float sm[4], ss[4];
    if (lane == 0) sm[wave] = mx;
    __syncthreads();
    mx = fmaxf(fmaxf(sm[0], sm[1]), fmaxf(sm[2], sm[3]));

    float sum = 0.f;
#pragma unroll
    for (int i = 0; i < 8; ++i) { x[i] = __expf(x[i] - mx); sum += x[i]; }
#pragma unroll
    for (int off = 32; off; off >>= 1) sum += __shfl_xor(sum, off);
    if (lane == 0) ss[wave] = sum;
    __syncthreads();
    const float inv = 1.f / (ss[0] + ss[1] + ss[2] + ss[3]);

#pragma unroll
    for (int i = 0; i < 4; ++i) {
        const uint32_t lo = f2bf(x[2 * i] * inv);
        const uint32_t hi = f2bf(x[2 * i + 1] * inv);
        u[i] = lo | (hi << 16);
    }
    *(uint4*)(p + t * 8) = make_uint4(u[0], u[1], u[2], u[3]);
}

extern "C" void kernel_launch(void* const* d_in, const int* in_sizes, int n_in,
                              void* d_out, int out_size, void* d_ws, size_t ws_size,
                              hipStream_t stream)
{
    const float* x   = (const float*)d_in[0];
    const float* pos = (const float*)d_in[1];
    const float* Wq  = (const float*)d_in[2];
    const float* bq  = (const float*)d_in[3];
    const float* Wk  = (const float*)d_in[4];
    const float* bk  = (const float*)d_in[5];
    const float* Wv  = (const float*)d_in[6];
    const float* bv  = (const float*)d_in[7];
    const float* Wd  = (const float*)d_in[8];
    const float* bd  = (const float*)d_in[9];
    float* out = (float*)d_out;

    // workspace layout (bytes), total 153,092,096
    char* ws = (char*)d_ws;
    uint16_t* xb   = (uint16_t*)(ws);                 // 16,777,216  [16384,512]
    uint16_t* wqkv = (uint16_t*)(ws + 16777216);      //  1,572,864  [1536,512]
    uint16_t* wd   = (uint16_t*)(ws + 18350080);      //    524,288  [512,512]
    uint16_t* Qb   = (uint16_t*)(ws + 18874368);      // 16,777,216  [16384,512]
    uint16_t* Kb   = (uint16_t*)(ws + 35651584);      // 16,777,216  [16384,512]
    uint16_t* Vt   = (uint16_t*)(ws + 52428800);      // 16,777,216  [8,512,2048]
    uint16_t* Pb   = (uint16_t*)(ws + 69206016);      // 67,108,864  [8,2048,2048]
    uint16_t* yb   = (uint16_t*)(ws + 136314880);     // 16,777,216  [16384,512]

    prep_x<<<4096, 256, 0, stream>>>(x, pos, xb);
    prep_w<<<512, 256, 0, stream>>>(Wq, Wk, Wv, Wd, wqkv, wd);

    // Q|K|Vt = xb @ wqkv^T (+bias):  M=16384, N=1536, K=512
    gemm_nt<3><<<dim3(12, 128, 1), 128, 0, stream>>>(
        xb, wqkv, Qb, Kb, Vt, bq, bk, bv, 1.0f, 512, 512, 0, 0, 0);

    // P[b] = (Q[b] @ K[b]^T) * scale:  8 x [2048,2048], K=512
    gemm_nt<0><<<dim3(16, 16, 8), 128, 0, stream>>>(
        Qb, Kb, Pb, nullptr, nullptr, nullptr, nullptr, nullptr,
        QK_SCALE, 512, 2048, (long)2048 * 512, (long)2048 * 512,
        (long)2048 * 2048);

    softmax_rows<<<16384, 256, 0, stream>>>(Pb);

    // y[b] = P[b] @ Vt[b]^T:  8 x [2048,512], K=2048
    gemm_nt<0><<<dim3(4, 16, 8), 128, 0, stream>>>(
        Pb, Vt, yb, nullptr, nullptr, nullptr, nullptr, nullptr,
        1.0f, 2048, 512, (long)2048 * 2048, (long)512 * 2048,
        (long)2048 * 512);

    // out = y @ wd^T + bd:  M=16384, N=512, K=512, fp32 out
    gemm_nt<2><<<dim3(4, 128, 1), 128, 0, stream>>>(
        yb, wd, out, nullptr, nullptr, bd, nullptr, nullptr,
        1.0f, 512, 512, 0, 0, 0);
}

// Round 3
// 314.623 us; speedup vs baseline: 1.1579x; 1.1579x over previous
//
#include <hip/hip_runtime.h>
#include <stdint.h>

typedef __bf16 bf16x8 __attribute__((ext_vector_type(8)));
typedef float f32x4 __attribute__((ext_vector_type(4)));

static constexpr float QK_SCALE = 0.044194173824159216f; // 1/sqrt(512)

__device__ __forceinline__ uint16_t f2bf(float f) {
    uint32_t x = __builtin_bit_cast(uint32_t, f);
    x += 0x7FFFu + ((x >> 16) & 1u);     // round-to-nearest-even; inputs finite
    return (uint16_t)(x >> 16);
}

// async 16B global->LDS copy (global_load_lds_dwordx4). LDS dest is
// wave-uniform base + lane*16; lds ptr = region_base + lane*16 matches.
__device__ __forceinline__ void cp16(const uint16_t* g, uint16_t* l) {
    __builtin_amdgcn_global_load_lds(
        (__attribute__((address_space(1))) void*)(uint16_t*)g,
        (__attribute__((address_space(3))) void*)l,
        16, 0, 0);
}

// ---------------------------------------------------------------------------
// NT GEMM: C[M,N] = A[M,K] * B[N,K]^T  (both operands K-contiguous, bf16)
// 128x128 block tile, BK=32, 256 threads = 4 waves (2x2), 64x64 per wave,
// mfma_f32_16x16x32_bf16. LDS double-buffered (2 x 16 KB), XOR-swizzled
// 16B chunks (slot col = kgroup ^ ((row>>1)&3)) -> 0 bank conflicts (R2).
// Pipeline: ONE barrier per K-iter; prefetch issued AFTER the barrier so the
// compiler's vmcnt(0)-before-s_barrier drains only the PREVIOUS iter's loads
// (needed anyway) while this iter's prefetch overlaps the MFMA phase.
// MODE 0: bf16 out, batched (blockIdx.z), scale, no bias
// MODE 2: f32 out + bias0 (final projection)
// MODE 3: QKV split epilogue: n<512 -> Q, <1024 -> K, else V transposed
// ---------------------------------------------------------------------------
template <int MODE>
__global__ __launch_bounds__(256, 3) void gemm_nt(
    const uint16_t* __restrict__ A, const uint16_t* __restrict__ Bm,
    void* __restrict__ C0, void* __restrict__ C1, void* __restrict__ C2,
    const float* __restrict__ bias0, const float* __restrict__ bias1,
    const float* __restrict__ bias2,
    float scale, int K, int ldc, long bsA, long bsB, long bsC)
{
    // per buffer: A slots 0..511 (elems 0..4095), B slots 512..1023
    __shared__ __align__(16) uint16_t SH[2][8192];

    const int t  = threadIdx.x;
    const int bn = blockIdx.x, bm = blockIdx.y, bz = blockIdx.z;
    const int wave = t >> 6, lane = t & 63;
    const int wm = (wave >> 1) * 64, wn = (wave & 1) * 64;
    const int lm = lane & 15, lq = lane >> 4;
    const int sw = lq ^ ((lm >> 1) & 3);          // read-side swizzled k-group

    const uint16_t* Ab = A  + (long)bz * bsA + (long)bm * 128 * K;
    const uint16_t* Bb = Bm + (long)bz * bsB + (long)bn * 128 * K;

    // staging: 4 cp16/thread/iter. slot s = j*256 + t covers region slots;
    // row r = s>>2, slot col cs = s&3, fetched global k-group cg = cs^((r>>1)&3)
    long goff[2]; int loff[2];
#pragma unroll
    for (int j = 0; j < 2; ++j) {
        const int s  = j * 256 + t;
        const int r  = s >> 2;
        const int cs = s & 3;
        const int cg = cs ^ ((r >> 1) & 3);
        goff[j] = (long)r * K + cg * 8;
        loff[j] = s * 8;
    }

    f32x4 acc[4][4] = {};

    // prologue: stage k0=0 into buffer 0
#pragma unroll
    for (int j = 0; j < 2; ++j) {
        cp16(Ab + goff[j], SH[0] + loff[j]);
        cp16(Bb + goff[j], SH[0] + 4096 + loff[j]);
    }

    int cur = 0;
    for (int k0 = 0; k0 < K; k0 += 32) {
        __syncthreads();   // drains prev-iter loads (vmcnt(0)) + guards reuse
        if (k0 + 32 < K) {
            const int nxt = cur ^ 1;
#pragma unroll
            for (int j = 0; j < 2; ++j) {
                cp16(Ab + goff[j] + k0 + 32, SH[nxt] + loff[j]);
                cp16(Bb + goff[j] + k0 + 32, SH[nxt] + 4096 + loff[j]);
            }
        }

        bf16x8 af[4], bfr[4];
#pragma unroll
        for (int i = 0; i < 4; ++i)               // A rows wm+i*16+lm
            af[i] = *(const bf16x8*)&SH[cur][((wm + i * 16 + lm) * 4 + sw) * 8];
#pragma unroll
        for (int j = 0; j < 4; ++j)               // B cols wn+j*16+lm
            bfr[j] = *(const bf16x8*)&SH[cur][4096 + ((wn + j * 16 + lm) * 4 + sw) * 8];
#pragma unroll
        for (int i = 0; i < 4; ++i)
#pragma unroll
            for (int j = 0; j < 4; ++j)
                acc[i][j] = __builtin_amdgcn_mfma_f32_16x16x32_bf16(
                    af[i], bfr[j], acc[i][j], 0, 0, 0);
        cur ^= 1;
    }

    // epilogue: C/D layout (m89/m91): m = lq*4 + reg (+i*16), n = lm (+j*16)
    const int mbase = bm * 128 + wm + lq * 4;
    const int nbase = bn * 128 + wn + lm;
#pragma unroll
    for (int i = 0; i < 4; ++i) {
#pragma unroll
        for (int j = 0; j < 4; ++j) {
            const int n = nbase + j * 16;
#pragma unroll
            for (int r = 0; r < 4; ++r) {
                const int m = mbase + i * 16 + r;
                const float v = acc[i][j][r] * scale;
                if (MODE == 0) {
                    ((uint16_t*)C0)[(long)bz * bsC + (long)m * ldc + n] = f2bf(v);
                } else if (MODE == 2) {
                    ((float*)C0)[(long)m * ldc + n] = v + bias0[n];
                } else { // MODE 3: QKV split (wave-uniform branch: 64 | 512)
                    const int sec = n >> 9;
                    const int nn  = n & 511;
                    if (sec == 0) {
                        ((uint16_t*)C0)[(long)m * 512 + nn] = f2bf(v + bias0[nn]);
                    } else if (sec == 1) {
                        ((uint16_t*)C1)[(long)m * 512 + nn] = f2bf(v + bias1[nn]);
                    } else { // V stored transposed per batch: Vt[b][d][s]
                        const int bb = m >> 11, ss = m & 2047;
                        ((uint16_t*)C2)[((long)bb * 512 + nn) * 2048 + ss] =
                            f2bf(v + bias2[nn]);
                    }
                }
            }
        }
    }
}

// x + pos_table -> bf16, 8 elems/thread, exact grid (4096 blocks)
__global__ __launch_bounds__(256) void prep_x(const float* __restrict__ x,
                                              const float* __restrict__ pos,
                                              uint16_t* __restrict__ xb)
{
    const long i8 = ((long)blockIdx.x * 256 + threadIdx.x) * 8;
    const long p8 = i8 & ((1l << 20) - 1);   // S*D = 2^20
    const float4* xv = (const float4*)(x + i8);
    const float4* pv = (const float4*)(pos + p8);
    const float4 a0 = xv[0], a1 = xv[1];
    const float4 b0 = pv[0], b1 = pv[1];
    uint16_t o[8];
    o[0] = f2bf(a0.x + b0.x); o[1] = f2bf(a0.y + b0.y);
    o[2] = f2bf(a0.z + b0.z); o[3] = f2bf(a0.w + b0.w);
    o[4] = f2bf(a1.x + b1.x); o[5] = f2bf(a1.y + b1.y);
    o[6] = f2bf(a1.z + b1.z); o[7] = f2bf(a1.w + b1.w);
    *(uint4*)(xb + i8) = *(uint4*)o;
}

// Wq,Wk,Wv -> stacked wqkv[1536,512] bf16; Wd -> wd bf16. 512 blocks exact.
__global__ __launch_bounds__(256) void prep_w(
    const float* __restrict__ Wq, const float* __restrict__ Wk,
    const float* __restrict__ Wv, const float* __restrict__ Wd,
    uint16_t* __restrict__ wqkv, uint16_t* __restrict__ wd)
{
    const long f = ((long)blockIdx.x * 256 + threadIdx.x) * 8;
    const int  w = (int)(f >> 18);          // 262144 elems per weight
    const long off = f & 262143;
    const float* src = (w == 0) ? Wq : (w == 1) ? Wk : (w == 2) ? Wv : Wd;
    uint16_t* dst = (w < 3) ? (wqkv + (long)w * 262144 + off) : (wd + off);
    const float4* s4 = (const float4*)(src + off);
    const float4 a = s4[0], b = s4[1];
    uint16_t o[8];
    o[0] = f2bf(a.x); o[1] = f2bf(a.y); o[2] = f2bf(a.z); o[3] = f2bf(a.w);
    o[4] = f2bf(b.x); o[5] = f2bf(b.y); o[6] = f2bf(b.z); o[7] = f2bf(b.w);
    *(uint4*)dst = *(uint4*)o;
}

// in-place row softmax over bf16 P rows of length 2048; 1 block (256 thr)/row
__global__ __launch_bounds__(256) void softmax_rows(uint16_t* __restrict__ P)
{
    uint16_t* p = P + (long)blockIdx.x * 2048;
    const int t = threadIdx.x;
    const int lane = t & 63, wave = t >> 6;

    uint4 raw = *(const uint4*)(p + t * 8);
    uint32_t u[4] = {raw.x, raw.y, raw.z, raw.w};
    float x[8];
#pragma unroll
    for (int i = 0; i < 4; ++i) {
        x[2 * i]     = __builtin_bit_cast(float, u[i] << 16);
        x[2 * i + 1] = __builtin_bit_cast(float, u[i] & 0xFFFF0000u);
    }
    float mx = x[0];
#pragma unroll
    for (int i = 1; i < 8; ++i) mx = fmaxf(mx, x[i]);
#pragma unroll
    for (int off = 32; off; off >>= 1) mx = fmaxf(mx, __shfl_xor(mx, off));
    __shared__ float sm[4], ss[4];
    if (lane == 0) sm[wave] = mx;
    __syncthreads();
    mx = fmaxf(fmaxf(sm[0], sm[1]), fmaxf(sm[2], sm[3]));

    float sum = 0.f;
#pragma unroll
    for (int i = 0; i < 8; ++i) { x[i] = __expf(x[i] - mx); sum += x[i]; }
#pragma unroll
    for (int off = 32; off; off >>= 1) sum += __shfl_xor(sum, off);
    if (lane == 0) ss[wave] = sum;
    __syncthreads();
    const float inv = 1.f / (ss[0] + ss[1] + ss[2] + ss[3]);

#pragma unroll
    for (int i = 0; i < 4; ++i) {
        const uint32_t lo = f2bf(x[2 * i] * inv);
        const uint32_t hi = f2bf(x[2 * i + 1] * inv);
        u[i] = lo | (hi << 16);
    }
    *(uint4*)(p + t * 8) = make_uint4(u[0], u[1], u[2], u[3]);
}

extern "C" void kernel_launch(void* const* d_in, const int* in_sizes, int n_in,
                              void* d_out, int out_size, void* d_ws, size_t ws_size,
                              hipStream_t stream)
{
    const float* x   = (const float*)d_in[0];
    const float* pos = (const float*)d_in[1];
    const float* Wq  = (const float*)d_in[2];
    const float* bq  = (const float*)d_in[3];
    const float* Wk  = (const float*)d_in[4];
    const float* bk  = (const float*)d_in[5];
    const float* Wv  = (const float*)d_in[6];
    const float* bv  = (const float*)d_in[7];
    const float* Wd  = (const float*)d_in[8];
    const float* bd  = (const float*)d_in[9];
    float* out = (float*)d_out;

    // workspace layout (bytes), total 153,092,096
    char* ws = (char*)d_ws;
    uint16_t* xb   = (uint16_t*)(ws);                 // 16,777,216  [16384,512]
    uint16_t* wqkv = (uint16_t*)(ws + 16777216);      //  1,572,864  [1536,512]
    uint16_t* wd   = (uint16_t*)(ws + 18350080);      //    524,288  [512,512]
    uint16_t* Qb   = (uint16_t*)(ws + 18874368);      // 16,777,216  [16384,512]
    uint16_t* Kb   = (uint16_t*)(ws + 35651584);      // 16,777,216  [16384,512]
    uint16_t* Vt   = (uint16_t*)(ws + 52428800);      // 16,777,216  [8,512,2048]
    uint16_t* Pb   = (uint16_t*)(ws + 69206016);      // 67,108,864  [8,2048,2048]
    uint16_t* yb   = (uint16_t*)(ws + 136314880);     // 16,777,216  [16384,512]

    prep_x<<<4096, 256, 0, stream>>>(x, pos, xb);
    prep_w<<<512, 256, 0, stream>>>(Wq, Wk, Wv, Wd, wqkv, wd);

    // Q|K|Vt = xb @ wqkv^T (+bias):  M=16384, N=1536, K=512
    gemm_nt<3><<<dim3(12, 128, 1), 256, 0, stream>>>(
        xb, wqkv, Qb, Kb, Vt, bq, bk, bv, 1.0f, 512, 512, 0, 0, 0);

    // P[b] = (Q[b] @ K[b]^T) * scale:  8 x [2048,2048], K=512
    gemm_nt<0><<<dim3(16, 16, 8), 256, 0, stream>>>(
        Qb, Kb, Pb, nullptr, nullptr, nullptr, nullptr, nullptr,
        QK_SCALE, 512, 2048, (long)2048 * 512, (long)2048 * 512,
        (long)2048 * 2048);

    softmax_rows<<<16384, 256, 0, stream>>>(Pb);

    // y[b] = P[b] @ Vt[b]^T:  8 x [2048,512], K=2048
    gemm_nt<0><<<dim3(4, 16, 8), 256, 0, stream>>>(
        Pb, Vt, yb, nullptr, nullptr, nullptr, nullptr, nullptr,
        1.0f, 2048, 512, (long)2048 * 2048, (long)512 * 2048,
        (long)2048 * 512);

    // out = y @ wd^T + bd:  M=16384, N=512, K=512, fp32 out
    gemm_nt<2><<<dim3(4, 128, 1), 256, 0, stream>>>(
        yb, wd, out, nullptr, nullptr, bd, nullptr, nullptr,
        1.0f, 512, 512, 0, 0, 0);
}

// Round 4
// 300.922 us; speedup vs baseline: 1.2106x; 1.0455x over previous
//
#include <hip/hip_runtime.h>
#include <stdint.h>

typedef __bf16 bf16x8 __attribute__((ext_vector_type(8)));
typedef float f32x4 __attribute__((ext_vector_type(4)));

static constexpr float QK_SCALE = 0.044194173824159216f; // 1/sqrt(512)

__device__ __forceinline__ uint16_t f2bf(float f) {
    uint32_t x = __builtin_bit_cast(uint32_t, f);
    x += 0x7FFFu + ((x >> 16) & 1u);     // round-to-nearest-even; inputs finite
    return (uint16_t)(x >> 16);
}

// async 16B global->LDS copy (global_load_lds_dwordx4). LDS dest is
// wave-uniform base + lane*16; lds ptr = region_base + lane*16 matches.
__device__ __forceinline__ void cp16(const uint16_t* g, uint16_t* l) {
    __builtin_amdgcn_global_load_lds(
        (__attribute__((address_space(1))) void*)(uint16_t*)g,
        (__attribute__((address_space(3))) void*)l,
        16, 0, 0);
}

// ---------------------------------------------------------------------------
// NT GEMM: C[M,N] = A[M,K] * B[N,K]^T  (both K-contiguous, bf16)
// 128x128 block tile, BK=32, 256 thr = 4 waves (2x2), 64x64/wave.
// 4-stage circular LDS pipeline (4 x 16 KB), XOR-swizzled 16B chunks
// (0 bank conflicts, verified R2). K-loop uses RAW s_barrier + hand
// s_waitcnt vmcnt(8): stages k+1..k+3 stay IN FLIGHT across the barrier
// (the __syncthreads vmcnt(0) drain is what flatlined R1/R3).
// Protocol safety: each wave waits its OWN vmcnt(8) (in-order retire =>
// its stage-k loads landed) + lgkmcnt(0) (its LDS reads sampled) BEFORE
// s_barrier; identical per-wave schedules make the barrier a proof that
// all waves' stage-k data is resident and buf (k+3)&3 is reusable.
// MFMA operands SWAPPED: acc holds C^T layout -> lane owns 4 consecutive n
// -> packed dwordx2/dwordx4 epilogue stores (was 64 scalar shorts).
// MODE 0: bf16 out, batched (blockIdx.z), scale, no bias
// MODE 2: f32 out + bias0 (final projection)
// MODE 3: QKV split epilogue: bn<4 -> Q, <8 -> K, else V transposed
// ---------------------------------------------------------------------------
template <int MODE>
__global__ __launch_bounds__(256, 2) void gemm_nt(
    const uint16_t* __restrict__ A, const uint16_t* __restrict__ Bm,
    void* __restrict__ C0, void* __restrict__ C1, void* __restrict__ C2,
    const float* __restrict__ bias0, const float* __restrict__ bias1,
    const float* __restrict__ bias2,
    float scale, int K, int ldc, long bsA, long bsB, long bsC)
{
    // 4 stages x (A 128x32 | B 128x32) = 4 x 16 KB
    __shared__ __align__(16) uint16_t SH[4][8192];

    const int t  = threadIdx.x;
    const int bn = blockIdx.x, bm = blockIdx.y, bz = blockIdx.z;
    const int wave = t >> 6, lane = t & 63;
    const int wm = (wave >> 1) * 64, wn = (wave & 1) * 64;
    const int lm = lane & 15, lq = lane >> 4;
    const int sw = lq ^ ((lm >> 1) & 3);          // read-side swizzled k-group

    const uint16_t* Ab = A  + (long)bz * bsA + (long)bm * 128 * K;
    const uint16_t* Bb = Bm + (long)bz * bsB + (long)bn * 128 * K;

    // staging map (R2-verified): slot s=j*256+t, row r=s>>2, slot col cs=s&3,
    // fetched k-group cg = cs ^ ((r>>1)&3); LDS addr = base + lane*16 (legal).
    long goff[2]; int loff[2];
#pragma unroll
    for (int j = 0; j < 2; ++j) {
        const int s  = j * 256 + t;
        const int r  = s >> 2;
        const int cs = s & 3;
        const int cg = cs ^ ((r >> 1) & 3);
        goff[j] = (long)r * K + cg * 8;
        loff[j] = s * 8;
    }

    const int KI = K >> 5;                        // 16 or 64 here

    // prologue: stages 0..2 in flight (12 cp16/thread outstanding)
#pragma unroll
    for (int st = 0; st < 3; ++st)
#pragma unroll
        for (int j = 0; j < 2; ++j) {
            cp16(Ab + goff[j] + st * 32, SH[st] + loff[j]);
            cp16(Bb + goff[j] + st * 32, SH[st] + 4096 + loff[j]);
        }

    f32x4 acc[4][4] = {};

    for (int k = 0; k < KI; ++k) {
        // my stage-k loads landed (12 outstanding -> oldest 4 retired) and my
        // LDS reads of buf (k+3)&3 (== k-1) are sampled; barrier extends both
        // guarantees block-wide. Stages k+1..k+3 remain in flight.
        asm volatile("s_waitcnt vmcnt(8) lgkmcnt(0)\n\ts_barrier" ::: "memory");

        int kp = k + 3; if (kp >= KI) kp -= KI;   // branch-free wrap (waste
        uint16_t* dst = SH[(k + 3) & 3];          //  3 stages/block, L2-hit)
        const long ko = (long)kp * 32;
#pragma unroll
        for (int j = 0; j < 2; ++j) {
            cp16(Ab + goff[j] + ko, dst + loff[j]);
            cp16(Bb + goff[j] + ko, dst + 4096 + loff[j]);
        }

        const uint16_t* buf = SH[k & 3];
        bf16x8 af[4], bfr[4];
#pragma unroll
        for (int i = 0; i < 4; ++i)               // A rows wm+i*16+lm
            af[i]  = *(const bf16x8*)&buf[((wm + i * 16 + lm) * 4 + sw) * 8];
#pragma unroll
        for (int i = 0; i < 4; ++i)               // B cols wn+i*16+lm
            bfr[i] = *(const bf16x8*)&buf[4096 + ((wn + i * 16 + lm) * 4 + sw) * 8];
#pragma unroll
        for (int i = 0; i < 4; ++i)
#pragma unroll
            for (int j = 0; j < 4; ++j)           // SWAPPED: D = C^T tile
                acc[i][j] = __builtin_amdgcn_mfma_f32_16x16x32_bf16(
                    bfr[i], af[j], acc[i][j], 0, 0, 0);
    }

    // epilogue: C^T layout -> lane holds n = nb+i*16+r (r=0..3 consecutive),
    // m = mb+j*16. Packed 8B/16B stores.
    const int mb = bm * 128 + wm + lm;
    const int nb = bn * 128 + wn + lq * 4;
#pragma unroll
    for (int i = 0; i < 4; ++i) {
        const int n = nb + i * 16;
        if (MODE == 0) {
#pragma unroll
            for (int j = 0; j < 4; ++j) {
                const int m = mb + j * 16;
                const uint32_t lo = (uint32_t)f2bf(acc[i][j][0] * scale) |
                                    ((uint32_t)f2bf(acc[i][j][1] * scale) << 16);
                const uint32_t hi = (uint32_t)f2bf(acc[i][j][2] * scale) |
                                    ((uint32_t)f2bf(acc[i][j][3] * scale) << 16);
                *(uint2*)&((uint16_t*)C0)[(long)bz * bsC + (long)m * ldc + n] =
                    make_uint2(lo, hi);
            }
        } else if (MODE == 2) {
            const float4 b4 = *(const float4*)&bias0[n];
#pragma unroll
            for (int j = 0; j < 4; ++j) {
                const int m = mb + j * 16;
                *(float4*)&((float*)C0)[(long)m * ldc + n] = make_float4(
                    acc[i][j][0] + b4.x, acc[i][j][1] + b4.y,
                    acc[i][j][2] + b4.z, acc[i][j][3] + b4.w);
            }
        } else { // MODE 3: whole block lives in one section (bn-uniform)
            const int sec = n >> 9, nn = n & 511;
            const float* bp = sec == 0 ? bias0 : (sec == 1 ? bias1 : bias2);
            const float4 b4 = *(const float4*)&bp[nn];
#pragma unroll
            for (int j = 0; j < 4; ++j) {
                const int m = mb + j * 16;
                if (sec < 2) {
                    uint16_t* Cq = (uint16_t*)(sec == 0 ? C0 : C1);
                    const uint32_t lo = (uint32_t)f2bf(acc[i][j][0] + b4.x) |
                                        ((uint32_t)f2bf(acc[i][j][1] + b4.y) << 16);
                    const uint32_t hi = (uint32_t)f2bf(acc[i][j][2] + b4.z) |
                                        ((uint32_t)f2bf(acc[i][j][3] + b4.w) << 16);
                    *(uint2*)&Cq[(long)m * 512 + nn] = make_uint2(lo, hi);
                } else { // V transposed: Vt[b][d][s], d = nn+r, s = m
                    const int bb = m >> 11, ss = m & 2047;
                    uint16_t* vt = (uint16_t*)C2 + ((long)bb * 512 + nn) * 2048 + ss;
                    vt[0]        = f2bf(acc[i][j][0] + b4.x);
                    vt[2048]     = f2bf(acc[i][j][1] + b4.y);
                    vt[2 * 2048] = f2bf(acc[i][j][2] + b4.z);
                    vt[3 * 2048] = f2bf(acc[i][j][3] + b4.w);
                }
            }
        }
    }
}

// x + pos_table -> bf16, 8 elems/thread, exact grid (4096 blocks)
__global__ __launch_bounds__(256) void prep_x(const float* __restrict__ x,
                                              const float* __restrict__ pos,
                                              uint16_t* __restrict__ xb)
{
    const long i8 = ((long)blockIdx.x * 256 + threadIdx.x) * 8;
    const long p8 = i8 & ((1l << 20) - 1);   // S*D = 2^20
    const float4* xv = (const float4*)(x + i8);
    const float4* pv = (const float4*)(pos + p8);
    const float4 a0 = xv[0], a1 = xv[1];
    const float4 b0 = pv[0], b1 = pv[1];
    uint16_t o[8];
    o[0] = f2bf(a0.x + b0.x); o[1] = f2bf(a0.y + b0.y);
    o[2] = f2bf(a0.z + b0.z); o[3] = f2bf(a0.w + b0.w);
    o[4] = f2bf(a1.x + b1.x); o[5] = f2bf(a1.y + b1.y);
    o[6] = f2bf(a1.z + b1.z); o[7] = f2bf(a1.w + b1.w);
    *(uint4*)(xb + i8) = *(uint4*)o;
}

// Wq,Wk,Wv -> stacked wqkv[1536,512] bf16; Wd -> wd bf16. 512 blocks exact.
__global__ __launch_bounds__(256) void prep_w(
    const float* __restrict__ Wq, const float* __restrict__ Wk,
    const float* __restrict__ Wv, const float* __restrict__ Wd,
    uint16_t* __restrict__ wqkv, uint16_t* __restrict__ wd)
{
    const long f = ((long)blockIdx.x * 256 + threadIdx.x) * 8;
    const int  w = (int)(f >> 18);          // 262144 elems per weight
    const long off = f & 262143;
    const float* src = (w == 0) ? Wq : (w == 1) ? Wk : (w == 2) ? Wv : Wd;
    uint16_t* dst = (w < 3) ? (wqkv + (long)w * 262144 + off) : (wd + off);
    const float4* s4 = (const float4*)(src + off);
    const float4 a = s4[0], b = s4[1];
    uint16_t o[8];
    o[0] = f2bf(a.x); o[1] = f2bf(a.y); o[2] = f2bf(a.z); o[3] = f2bf(a.w);
    o[4] = f2bf(b.x); o[5] = f2bf(b.y); o[6] = f2bf(b.z); o[7] = f2bf(b.w);
    *(uint4*)dst = *(uint4*)o;
}

// in-place row softmax over bf16 P rows of length 2048; 1 block (256 thr)/row
__global__ __launch_bounds__(256) void softmax_rows(uint16_t* __restrict__ P)
{
    uint16_t* p = P + (long)blockIdx.x * 2048;
    const int t = threadIdx.x;
    const int lane = t & 63, wave = t >> 6;

    uint4 raw = *(const uint4*)(p + t * 8);
    uint32_t u[4] = {raw.x, raw.y, raw.z, raw.w};
    float x[8];
#pragma unroll
    for (int i = 0; i < 4; ++i) {
        x[2 * i]     = __builtin_bit_cast(float, u[i] << 16);
        x[2 * i + 1] = __builtin_bit_cast(float, u[i] & 0xFFFF0000u);
    }
    float mx = x[0];
#pragma unroll
    for (int i = 1; i < 8; ++i) mx = fmaxf(mx, x[i]);
#pragma unroll
    for (int off = 32; off; off >>= 1) mx = fmaxf(mx, __shfl_xor(mx, off));
    __shared__ float sm[4], ss[4];
    if (lane == 0) sm[wave] = mx;
    __syncthreads();
    mx = fmaxf(fmaxf(sm[0], sm[1]), fmaxf(sm[2], sm[3]));

    float sum = 0.f;
#pragma unroll
    for (int i = 0; i < 8; ++i) { x[i] = __expf(x[i] - mx); sum += x[i]; }
#pragma unroll
    for (int off = 32; off; off >>= 1) sum += __shfl_xor(sum, off);
    if (lane == 0) ss[wave] = sum;
    __syncthreads();
    const float inv = 1.f / (ss[0] + ss[1] + ss[2] + ss[3]);

#pragma unroll
    for (int i = 0; i < 4; ++i) {
        const uint32_t lo = f2bf(x[2 * i] * inv);
        const uint32_t hi = f2bf(x[2 * i + 1] * inv);
        u[i] = lo | (hi << 16);
    }
    *(uint4*)(p + t * 8) = make_uint4(u[0], u[1], u[2], u[3]);
}

extern "C" void kernel_launch(void* const* d_in, const int* in_sizes, int n_in,
                              void* d_out, int out_size, void* d_ws, size_t ws_size,
                              hipStream_t stream)
{
    const float* x   = (const float*)d_in[0];
    const float* pos = (const float*)d_in[1];
    const float* Wq  = (const float*)d_in[2];
    const float* bq  = (const float*)d_in[3];
    const float* Wk  = (const float*)d_in[4];
    const float* bk  = (const float*)d_in[5];
    const float* Wv  = (const float*)d_in[6];
    const float* bv  = (const float*)d_in[7];
    const float* Wd  = (const float*)d_in[8];
    const float* bd  = (const float*)d_in[9];
    float* out = (float*)d_out;

    // workspace layout (bytes), total 153,092,096
    char* ws = (char*)d_ws;
    uint16_t* xb   = (uint16_t*)(ws);                 // 16,777,216  [16384,512]
    uint16_t* wqkv = (uint16_t*)(ws + 16777216);      //  1,572,864  [1536,512]
    uint16_t* wd   = (uint16_t*)(ws + 18350080);      //    524,288  [512,512]
    uint16_t* Qb   = (uint16_t*)(ws + 18874368);      // 16,777,216  [16384,512]
    uint16_t* Kb   = (uint16_t*)(ws + 35651584);      // 16,777,216  [16384,512]
    uint16_t* Vt   = (uint16_t*)(ws + 52428800);      // 16,777,216  [8,512,2048]
    uint16_t* Pb   = (uint16_t*)(ws + 69206016);      // 67,108,864  [8,2048,2048]
    uint16_t* yb   = (uint16_t*)(ws + 136314880);     // 16,777,216  [16384,512]

    prep_x<<<4096, 256, 0, stream>>>(x, pos, xb);
    prep_w<<<512, 256, 0, stream>>>(Wq, Wk, Wv, Wd, wqkv, wd);

    // Q|K|Vt = xb @ wqkv^T (+bias):  M=16384, N=1536, K=512
    gemm_nt<3><<<dim3(12, 128, 1), 256, 0, stream>>>(
        xb, wqkv, Qb, Kb, Vt, bq, bk, bv, 1.0f, 512, 512, 0, 0, 0);

    // P[b] = (Q[b] @ K[b]^T) * scale:  8 x [2048,2048], K=512
    gemm_nt<0><<<dim3(16, 16, 8), 256, 0, stream>>>(
        Qb, Kb, Pb, nullptr, nullptr, nullptr, nullptr, nullptr,
        QK_SCALE, 512, 2048, (long)2048 * 512, (long)2048 * 512,
        (long)2048 * 2048);

    softmax_rows<<<16384, 256, 0, stream>>>(Pb);

    // y[b] = P[b] @ Vt[b]^T:  8 x [2048,512], K=2048
    gemm_nt<0><<<dim3(4, 16, 8), 256, 0, stream>>>(
        Pb, Vt, yb, nullptr, nullptr, nullptr, nullptr, nullptr,
        1.0f, 2048, 512, (long)2048 * 2048, (long)512 * 2048,
        (long)2048 * 512);

    // out = y @ wd^T + bd:  M=16384, N=512, K=512, fp32 out
    gemm_nt<2><<<dim3(4, 128, 1), 256, 0, stream>>>(
        yb, wd, out, nullptr, nullptr, bd, nullptr, nullptr,
        1.0f, 512, 512, 0, 0, 0);
}

// Round 5
// 284.475 us; speedup vs baseline: 1.2806x; 1.0578x over previous
//
#include <hip/hip_runtime.h>
#include <stdint.h>

typedef __bf16 bf16x8 __attribute__((ext_vector_type(8)));
typedef float f32x4 __attribute__((ext_vector_type(4)));

static constexpr float QK_SCALE = 0.044194173824159216f; // 1/sqrt(512)

__device__ __forceinline__ uint16_t f2bf(float f) {
    uint32_t x = __builtin_bit_cast(uint32_t, f);
    x += 0x7FFFu + ((x >> 16) & 1u);     // round-to-nearest-even; inputs finite
    return (uint16_t)(x >> 16);
}

// async 16B global->LDS copy (global_load_lds_dwordx4). LDS dest is
// wave-uniform base + lane*16; lds ptr = region_base + lane*16 matches.
__device__ __forceinline__ void cp16(const uint16_t* g, uint16_t* l) {
    __builtin_amdgcn_global_load_lds(
        (__attribute__((address_space(1))) void*)(uint16_t*)g,
        (__attribute__((address_space(3))) void*)l,
        16, 0, 0);
}

// ---------------------------------------------------------------------------
// NT GEMM: C[M,N] = A[M,K] * B[N,K]^T  (both K-contiguous, bf16)
// 128x128 block tile, BK=32, 256 thr = 4 waves (2x2), 64x64/wave.
// 4-stage circular LDS pipeline (4 x 16 KB = 64 KB), XOR-swizzled 16B chunks
// (0 bank conflicts, R2-verified). K-loop: RAW s_barrier + s_waitcnt vmcnt(8)
// so stages k+1..k+3 stay in flight across the barrier (R4: 85->65 us).
// R5: XCD-aware supertile swizzle. Grid flattened to 1-D; id&7 = XCD
// (round-robin, m09). Each XCD walks whole 4x4 supertiles so the 16 blocks
// sharing 4 A-strips + 4 B-strips (1 MB) run on ONE XCD -> staging served
// from that XCD's 4 MB L2 (34.5 TB/s) instead of LLC (~8 TB/s, the R4 wall).
// Tail prefetch clamps to last stage (L1-hot) instead of wrapping to cold
// stage 0 (R4's +21 MB HBM refetch).
// MODE 0: bf16 out, batched, scale, no bias
// MODE 2: f32 out + bias0 (final projection)
// MODE 3: QKV split epilogue: n<512 -> Q, <1024 -> K, else V transposed
// ---------------------------------------------------------------------------
template <int MODE>
__global__ __launch_bounds__(256, 2) void gemm_nt(
    const uint16_t* __restrict__ A, const uint16_t* __restrict__ Bm,
    void* __restrict__ C0, void* __restrict__ C1, void* __restrict__ C2,
    const float* __restrict__ bias0, const float* __restrict__ bias1,
    const float* __restrict__ bias2,
    float scale, int K, int ldc, long bsA, long bsB, long bsC,
    int scols, int stPerBatch)
{
    // 4 stages x (A 128x32 | B 128x32) = 4 x 16 KB
    __shared__ __align__(16) uint16_t SH[4][8192];

    // --- supertile decode: id -> (bm, bn, bz) ------------------------------
    const uint32_t id  = blockIdx.x;
    const uint32_t xcd = id & 7u;
    const uint32_t p   = id >> 3;          // per-XCD sequence
    const uint32_t q   = p >> 4;           // local supertile index
    const uint32_t w   = p & 15u;          // position within 4x4 supertile
    const uint32_t g   = q * 8u + xcd;     // global supertile id
    const uint32_t bz  = g / (uint32_t)stPerBatch;
    const uint32_t gs  = g - bz * (uint32_t)stPerBatch;
    const uint32_t sr  = gs / (uint32_t)scols;
    const uint32_t sc  = gs - sr * (uint32_t)scols;
    const int bm = (int)(sr * 4u + (w >> 2));
    const int bn = (int)(sc * 4u + (w & 3u));
    // -----------------------------------------------------------------------

    const int t  = threadIdx.x;
    const int wave = t >> 6, lane = t & 63;
    const int wm = (wave >> 1) * 64, wn = (wave & 1) * 64;
    const int lm = lane & 15, lq = lane >> 4;
    const int sw = lq ^ ((lm >> 1) & 3);          // read-side swizzled k-group

    const uint16_t* Ab = A  + (long)bz * bsA + (long)bm * 128 * K;
    const uint16_t* Bb = Bm + (long)bz * bsB + (long)bn * 128 * K;

    // staging map (R2-verified): slot s=j*256+t, row r=s>>2, slot col cs=s&3,
    // fetched k-group cg = cs ^ ((r>>1)&3); LDS addr = base + lane*16 (legal).
    long goff[2]; int loff[2];
#pragma unroll
    for (int j = 0; j < 2; ++j) {
        const int s  = j * 256 + t;
        const int r  = s >> 2;
        const int cs = s & 3;
        const int cg = cs ^ ((r >> 1) & 3);
        goff[j] = (long)r * K + cg * 8;
        loff[j] = s * 8;
    }

    const int KI = K >> 5;                        // 16 or 64 here

    // prologue: stages 0..2 in flight (12 cp16/thread outstanding)
#pragma unroll
    for (int st = 0; st < 3; ++st)
#pragma unroll
        for (int j = 0; j < 2; ++j) {
            cp16(Ab + goff[j] + st * 32, SH[st] + loff[j]);
            cp16(Bb + goff[j] + st * 32, SH[st] + 4096 + loff[j]);
        }

    f32x4 acc[4][4] = {};

    for (int k = 0; k < KI; ++k) {
        // my stage-k loads landed (12 outstanding -> oldest 4 retired) and my
        // LDS reads of buf (k+3)&3 (== k-1) are sampled; barrier extends both
        // guarantees block-wide. Stages k+1..k+3 remain in flight.
        asm volatile("s_waitcnt vmcnt(8) lgkmcnt(0)\n\ts_barrier" ::: "memory");

        int kp = k + 3; if (kp >= KI) kp = KI - 1; // tail: refetch hot tile
        uint16_t* dst = SH[(k + 3) & 3];
        const long ko = (long)kp * 32;
#pragma unroll
        for (int j = 0; j < 2; ++j) {
            cp16(Ab + goff[j] + ko, dst + loff[j]);
            cp16(Bb + goff[j] + ko, dst + 4096 + loff[j]);
        }

        const uint16_t* buf = SH[k & 3];
        bf16x8 af[4], bfr[4];
#pragma unroll
        for (int i = 0; i < 4; ++i)               // A rows wm+i*16+lm
            af[i]  = *(const bf16x8*)&buf[((wm + i * 16 + lm) * 4 + sw) * 8];
#pragma unroll
        for (int i = 0; i < 4; ++i)               // B cols wn+i*16+lm
            bfr[i] = *(const bf16x8*)&buf[4096 + ((wn + i * 16 + lm) * 4 + sw) * 8];
#pragma unroll
        for (int i = 0; i < 4; ++i)
#pragma unroll
            for (int j = 0; j < 4; ++j)           // SWAPPED: D = C^T tile
                acc[i][j] = __builtin_amdgcn_mfma_f32_16x16x32_bf16(
                    bfr[i], af[j], acc[i][j], 0, 0, 0);
    }

    // epilogue: C^T layout -> lane holds n = nb+i*16+r (r=0..3 consecutive),
    // m = mb+j*16. Packed 8B/16B stores.
    const int mb = bm * 128 + wm + lm;
    const int nb = bn * 128 + wn + lq * 4;
#pragma unroll
    for (int i = 0; i < 4; ++i) {
        const int n = nb + i * 16;
        if (MODE == 0) {
#pragma unroll
            for (int j = 0; j < 4; ++j) {
                const int m = mb + j * 16;
                const uint32_t lo = (uint32_t)f2bf(acc[i][j][0] * scale) |
                                    ((uint32_t)f2bf(acc[i][j][1] * scale) << 16);
                const uint32_t hi = (uint32_t)f2bf(acc[i][j][2] * scale) |
                                    ((uint32_t)f2bf(acc[i][j][3] * scale) << 16);
                *(uint2*)&((uint16_t*)C0)[(long)bz * bsC + (long)m * ldc + n] =
                    make_uint2(lo, hi);
            }
        } else if (MODE == 2) {
            const float4 b4 = *(const float4*)&bias0[n];
#pragma unroll
            for (int j = 0; j < 4; ++j) {
                const int m = mb + j * 16;
                *(float4*)&((float*)C0)[(long)m * ldc + n] = make_float4(
                    acc[i][j][0] + b4.x, acc[i][j][1] + b4.y,
                    acc[i][j][2] + b4.z, acc[i][j][3] + b4.w);
            }
        } else { // MODE 3: whole block lives in one section (bn-uniform)
            const int sec = n >> 9, nn = n & 511;
            const float* bp = sec == 0 ? bias0 : (sec == 1 ? bias1 : bias2);
            const float4 b4 = *(const float4*)&bp[nn];
#pragma unroll
            for (int j = 0; j < 4; ++j) {
                const int m = mb + j * 16;
                if (sec < 2) {
                    uint16_t* Cq = (uint16_t*)(sec == 0 ? C0 : C1);
                    const uint32_t lo = (uint32_t)f2bf(acc[i][j][0] + b4.x) |
                                        ((uint32_t)f2bf(acc[i][j][1] + b4.y) << 16);
                    const uint32_t hi = (uint32_t)f2bf(acc[i][j][2] + b4.z) |
                                        ((uint32_t)f2bf(acc[i][j][3] + b4.w) << 16);
                    *(uint2*)&Cq[(long)m * 512 + nn] = make_uint2(lo, hi);
                } else { // V transposed: Vt[b][d][s], d = nn+r, s = m
                    const int bb = m >> 11, ss = m & 2047;
                    uint16_t* vt = (uint16_t*)C2 + ((long)bb * 512 + nn) * 2048 + ss;
                    vt[0]        = f2bf(acc[i][j][0] + b4.x);
                    vt[2048]     = f2bf(acc[i][j][1] + b4.y);
                    vt[2 * 2048] = f2bf(acc[i][j][2] + b4.z);
                    vt[3 * 2048] = f2bf(acc[i][j][3] + b4.w);
                }
            }
        }
    }
}

// x + pos_table -> bf16, 8 elems/thread, exact grid (4096 blocks)
__global__ __launch_bounds__(256) void prep_x(const float* __restrict__ x,
                                              const float* __restrict__ pos,
                                              uint16_t* __restrict__ xb)
{
    const long i8 = ((long)blockIdx.x * 256 + threadIdx.x) * 8;
    const long p8 = i8 & ((1l << 20) - 1);   // S*D = 2^20
    const float4* xv = (const float4*)(x + i8);
    const float4* pv = (const float4*)(pos + p8);
    const float4 a0 = xv[0], a1 = xv[1];
    const float4 b0 = pv[0], b1 = pv[1];
    uint16_t o[8];
    o[0] = f2bf(a0.x + b0.x); o[1] = f2bf(a0.y + b0.y);
    o[2] = f2bf(a0.z + b0.z); o[3] = f2bf(a0.w + b0.w);
    o[4] = f2bf(a1.x + b1.x); o[5] = f2bf(a1.y + b1.y);
    o[6] = f2bf(a1.z + b1.z); o[7] = f2bf(a1.w + b1.w);
    *(uint4*)(xb + i8) = *(uint4*)o;
}

// Wq,Wk,Wv -> stacked wqkv[1536,512] bf16; Wd -> wd bf16. 512 blocks exact.
__global__ __launch_bounds__(256) void prep_w(
    const float* __restrict__ Wq, const float* __restrict__ Wk,
    const float* __restrict__ Wv, const float* __restrict__ Wd,
    uint16_t* __restrict__ wqkv, uint16_t* __restrict__ wd)
{
    const long f = ((long)blockIdx.x * 256 + threadIdx.x) * 8;
    const int  w = (int)(f >> 18);          // 262144 elems per weight
    const long off = f & 262143;
    const float* src = (w == 0) ? Wq : (w == 1) ? Wk : (w == 2) ? Wv : Wd;
    uint16_t* dst = (w < 3) ? (wqkv + (long)w * 262144 + off) : (wd + off);
    const float4* s4 = (const float4*)(src + off);
    const float4 a = s4[0], b = s4[1];
    uint16_t o[8];
    o[0] = f2bf(a.x); o[1] = f2bf(a.y); o[2] = f2bf(a.z); o[3] = f2bf(a.w);
    o[4] = f2bf(b.x); o[5] = f2bf(b.y); o[6] = f2bf(b.z); o[7] = f2bf(b.w);
    *(uint4*)dst = *(uint4*)o;
}

// in-place row softmax over bf16 P rows of length 2048; 1 block (256 thr)/row
__global__ __launch_bounds__(256) void softmax_rows(uint16_t* __restrict__ P)
{
    uint16_t* p = P + (long)blockIdx.x * 2048;
    const int t = threadIdx.x;
    const int lane = t & 63, wave = t >> 6;

    uint4 raw = *(const uint4*)(p + t * 8);
    uint32_t u[4] = {raw.x, raw.y, raw.z, raw.w};
    float x[8];
#pragma unroll
    for (int i = 0; i < 4; ++i) {
        x[2 * i]     = __builtin_bit_cast(float, u[i] << 16);
        x[2 * i + 1] = __builtin_bit_cast(float, u[i] & 0xFFFF0000u);
    }
    float mx = x[0];
#pragma unroll
    for (int i = 1; i < 8; ++i) mx = fmaxf(mx, x[i]);
#pragma unroll
    for (int off = 32; off; off >>= 1) mx = fmaxf(mx, __shfl_xor(mx, off));
    __shared__ float sm[4], ss[4];
    if (lane == 0) sm[wave] = mx;
    __syncthreads();
    mx = fmaxf(fmaxf(sm[0], sm[1]), fmaxf(sm[2], sm[3]));

    float sum = 0.f;
#pragma unroll
    for (int i = 0; i < 8; ++i) { x[i] = __expf(x[i] - mx); sum += x[i]; }
#pragma unroll
    for (int off = 32; off; off >>= 1) sum += __shfl_xor(sum, off);
    if (lane == 0) ss[wave] = sum;
    __syncthreads();
    const float inv = 1.f / (ss[0] + ss[1] + ss[2] + ss[3]);

#pragma unroll
    for (int i = 0; i < 4; ++i) {
        const uint32_t lo = f2bf(x[2 * i] * inv);
        const uint32_t hi = f2bf(x[2 * i + 1] * inv);
        u[i] = lo | (hi << 16);
    }
    *(uint4*)(p + t * 8) = make_uint4(u[0], u[1], u[2], u[3]);
}

extern "C" void kernel_launch(void* const* d_in, const int* in_sizes, int n_in,
                              void* d_out, int out_size, void* d_ws, size_t ws_size,
                              hipStream_t stream)
{
    const float* x   = (const float*)d_in[0];
    const float* pos = (const float*)d_in[1];
    const float* Wq  = (const float*)d_in[2];
    const float* bq  = (const float*)d_in[3];
    const float* Wk  = (const float*)d_in[4];
    const float* bk  = (const float*)d_in[5];
    const float* Wv  = (const float*)d_in[6];
    const float* bv  = (const float*)d_in[7];
    const float* Wd  = (const float*)d_in[8];
    const float* bd  = (const float*)d_in[9];
    float* out = (float*)d_out;

    // workspace layout (bytes), total 153,092,096
    char* ws = (char*)d_ws;
    uint16_t* xb   = (uint16_t*)(ws);                 // 16,777,216  [16384,512]
    uint16_t* wqkv = (uint16_t*)(ws + 16777216);      //  1,572,864  [1536,512]
    uint16_t* wd   = (uint16_t*)(ws + 18350080);      //    524,288  [512,512]
    uint16_t* Qb   = (uint16_t*)(ws + 18874368);      // 16,777,216  [16384,512]
    uint16_t* Kb   = (uint16_t*)(ws + 35651584);      // 16,777,216  [16384,512]
    uint16_t* Vt   = (uint16_t*)(ws + 52428800);      // 16,777,216  [8,512,2048]
    uint16_t* Pb   = (uint16_t*)(ws + 69206016);      // 67,108,864  [8,2048,2048]
    uint16_t* yb   = (uint16_t*)(ws + 136314880);     // 16,777,216  [16384,512]

    prep_x<<<4096, 256, 0, stream>>>(x, pos, xb);
    prep_w<<<512, 256, 0, stream>>>(Wq, Wk, Wv, Wd, wqkv, wd);

    // Q|K|Vt = xb @ wqkv^T (+bias):  M=16384, N=1536, K=512
    // gm=128, gn=12 -> scols=3, stPerBatch=32*3=96, blocks=1536
    gemm_nt<3><<<1536, 256, 0, stream>>>(
        xb, wqkv, Qb, Kb, Vt, bq, bk, bv, 1.0f, 512, 512, 0, 0, 0, 3, 96);

    // P[b] = (Q[b] @ K[b]^T) * scale:  8 x [2048,2048], K=512
    // per batch gm=16, gn=16 -> scols=4, stPerBatch=16, blocks=2048
    gemm_nt<0><<<2048, 256, 0, stream>>>(
        Qb, Kb, Pb, nullptr, nullptr, nullptr, nullptr, nullptr,
        QK_SCALE, 512, 2048, (long)2048 * 512, (long)2048 * 512,
        (long)2048 * 2048, 4, 16);

    softmax_rows<<<16384, 256, 0, stream>>>(Pb);

    // y[b] = P[b] @ Vt[b]^T:  8 x [2048,512], K=2048
    // per batch gm=16, gn=4 -> scols=1, stPerBatch=4, blocks=512
    gemm_nt<0><<<512, 256, 0, stream>>>(
        Pb, Vt, yb, nullptr, nullptr, nullptr, nullptr, nullptr,
        1.0f, 2048, 512, (long)2048 * 2048, (long)512 * 2048,
        (long)2048 * 512, 1, 4);

    // out = y @ wd^T + bd:  M=16384, N=512, K=512, fp32 out
    // gm=128, gn=4 -> scols=1, stPerBatch=32, blocks=512
    gemm_nt<2><<<512, 256, 0, stream>>>(
        yb, wd, out, nullptr, nullptr, bd, nullptr, nullptr,
        1.0f, 512, 512, 0, 0, 0, 1, 32);
}

// Round 6
// 280.221 us; speedup vs baseline: 1.3000x; 1.0152x over previous
//
#include <hip/hip_runtime.h>
#include <stdint.h>

typedef __bf16 bf16x8 __attribute__((ext_vector_type(8)));
typedef float f32x4 __attribute__((ext_vector_type(4)));

static constexpr float QK_SCALE = 0.044194173824159216f; // 1/sqrt(512)

__device__ __forceinline__ uint16_t f2bf(float f) {
    uint32_t x = __builtin_bit_cast(uint32_t, f);
    x += 0x7FFFu + ((x >> 16) & 1u);     // round-to-nearest-even; inputs finite
    return (uint16_t)(x >> 16);
}

// async 16B global->LDS copy (global_load_lds_dwordx4). LDS dest is
// wave-uniform base + lane*16; lds ptr = region_base + lane*16 matches.
__device__ __forceinline__ void cp16(const uint16_t* g, uint16_t* l) {
    __builtin_amdgcn_global_load_lds(
        (__attribute__((address_space(1))) void*)(uint16_t*)g,
        (__attribute__((address_space(3))) void*)l,
        16, 0, 0);
}

// ---------------------------------------------------------------------------
// NT GEMM: C[M,N] = A[M,K] * B[N,K]^T  (both K-contiguous, bf16)
// 128x128 block tile, BK=32, 256 thr = 4 waves (2x2), 64x64/wave.
// R6: 3-stage circular LDS pipeline (3 x 16 KB = 48 KB) -> 3 blocks/CU
// (R5's 4-stage/64KB capped us at 2 blocks/CU = the m132 occupancy cliff;
// R5 showed latency exposure, not cache BW, is the limiter).
// K-loop: RAW s_barrier + s_waitcnt vmcnt(4): stage k+1 and the just-issued
// k+2 stay in flight across the barrier (~2 iter periods of latency slack).
// XOR-swizzled 16B chunks (0 bank conflicts, R2-verified). XCD supertile
// swizzle (R5: FETCH 90->49 MB). Tail prefetch clamps to last stage.
// MFMA operands swapped -> C^T layout -> packed dwordx2/x4 stores (R4).
// MODE 0: bf16 out, batched, scale, no bias
// MODE 2: f32 out + bias0 (final projection)
// MODE 3: QKV split epilogue: n<512 -> Q, <1024 -> K, else V transposed
// ---------------------------------------------------------------------------
template <int MODE>
__global__ __launch_bounds__(256, 3) void gemm_nt(
    const uint16_t* __restrict__ A, const uint16_t* __restrict__ Bm,
    void* __restrict__ C0, void* __restrict__ C1, void* __restrict__ C2,
    const float* __restrict__ bias0, const float* __restrict__ bias1,
    const float* __restrict__ bias2,
    float scale, int K, int ldc, long bsA, long bsB, long bsC,
    int scols, int stPerBatch)
{
    // 3 stages x (A 128x32 | B 128x32) = 3 x 16 KB
    __shared__ __align__(16) uint16_t SH[3][8192];

    // --- supertile decode: id -> (bm, bn, bz) ------------------------------
    const uint32_t id  = blockIdx.x;
    const uint32_t xcd = id & 7u;
    const uint32_t p   = id >> 3;          // per-XCD sequence
    const uint32_t q   = p >> 4;           // local supertile index
    const uint32_t w   = p & 15u;          // position within 4x4 supertile
    const uint32_t g   = q * 8u + xcd;     // global supertile id
    const uint32_t bz  = g / (uint32_t)stPerBatch;
    const uint32_t gs  = g - bz * (uint32_t)stPerBatch;
    const uint32_t sr  = gs / (uint32_t)scols;
    const uint32_t sc  = gs - sr * (uint32_t)scols;
    const int bm = (int)(sr * 4u + (w >> 2));
    const int bn = (int)(sc * 4u + (w & 3u));
    // -----------------------------------------------------------------------

    const int t  = threadIdx.x;
    const int wave = t >> 6, lane = t & 63;
    const int wm = (wave >> 1) * 64, wn = (wave & 1) * 64;
    const int lm = lane & 15, lq = lane >> 4;
    const int sw = lq ^ ((lm >> 1) & 3);          // read-side swizzled k-group

    const uint16_t* Ab = A  + (long)bz * bsA + (long)bm * 128 * K;
    const uint16_t* Bb = Bm + (long)bz * bsB + (long)bn * 128 * K;

    // staging map (R2-verified): slot s=j*256+t, row r=s>>2, slot col cs=s&3,
    // fetched k-group cg = cs ^ ((r>>1)&3); LDS addr = base + lane*16 (legal).
    long goff[2]; int loff[2];
#pragma unroll
    for (int j = 0; j < 2; ++j) {
        const int s  = j * 256 + t;
        const int r  = s >> 2;
        const int cs = s & 3;
        const int cg = cs ^ ((r >> 1) & 3);
        goff[j] = (long)r * K + cg * 8;
        loff[j] = s * 8;
    }

    const int KI = K >> 5;                        // 16 or 64 here

    // prologue: stages 0,1 in flight (8 cp16/thread outstanding)
#pragma unroll
    for (int st = 0; st < 2; ++st)
#pragma unroll
        for (int j = 0; j < 2; ++j) {
            cp16(Ab + goff[j] + st * 32, SH[st] + loff[j]);
            cp16(Bb + goff[j] + st * 32, SH[st] + 4096 + loff[j]);
        }

    f32x4 acc[4][4] = {};

    int cur = 0, pf = 2;                          // buf k%3, (k+2)%3
    for (int k = 0; k < KI; ++k) {
        // my stage-k loads landed (8 outstanding -> oldest 4 retired) and my
        // LDS reads of buf (k+2)%3 (== k-1) are sampled; barrier extends both
        // guarantees block-wide. Stages k+1, k+2 remain in flight.
        asm volatile("s_waitcnt vmcnt(4) lgkmcnt(0)\n\ts_barrier" ::: "memory");

        int kp = k + 2; if (kp >= KI) kp = KI - 1; // tail: refetch hot tile
        uint16_t* dst = SH[pf];
        const long ko = (long)kp * 32;
#pragma unroll
        for (int j = 0; j < 2; ++j) {
            cp16(Ab + goff[j] + ko, dst + loff[j]);
            cp16(Bb + goff[j] + ko, dst + 4096 + loff[j]);
        }

        const uint16_t* buf = SH[cur];
        bf16x8 af[4], bfr[4];
#pragma unroll
        for (int i = 0; i < 4; ++i)               // A rows wm+i*16+lm
            af[i]  = *(const bf16x8*)&buf[((wm + i * 16 + lm) * 4 + sw) * 8];
#pragma unroll
        for (int i = 0; i < 4; ++i)               // B cols wn+i*16+lm
            bfr[i] = *(const bf16x8*)&buf[4096 + ((wn + i * 16 + lm) * 4 + sw) * 8];
#pragma unroll
        for (int i = 0; i < 4; ++i)
#pragma unroll
            for (int j = 0; j < 4; ++j)           // SWAPPED: D = C^T tile
                acc[i][j] = __builtin_amdgcn_mfma_f32_16x16x32_bf16(
                    bfr[i], af[j], acc[i][j], 0, 0, 0);

        cur = (cur == 2) ? 0 : cur + 1;
        pf  = (pf  == 2) ? 0 : pf  + 1;
    }

    // epilogue: C^T layout -> lane holds n = nb+i*16+r (r=0..3 consecutive),
    // m = mb+j*16. Packed 8B/16B stores.
    const int mb = bm * 128 + wm + lm;
    const int nb = bn * 128 + wn + lq * 4;
#pragma unroll
    for (int i = 0; i < 4; ++i) {
        const int n = nb + i * 16;
        if (MODE == 0) {
#pragma unroll
            for (int j = 0; j < 4; ++j) {
                const int m = mb + j * 16;
                const uint32_t lo = (uint32_t)f2bf(acc[i][j][0] * scale) |
                                    ((uint32_t)f2bf(acc[i][j][1] * scale) << 16);
                const uint32_t hi = (uint32_t)f2bf(acc[i][j][2] * scale) |
                                    ((uint32_t)f2bf(acc[i][j][3] * scale) << 16);
                *(uint2*)&((uint16_t*)C0)[(long)bz * bsC + (long)m * ldc + n] =
                    make_uint2(lo, hi);
            }
        } else if (MODE == 2) {
            const float4 b4 = *(const float4*)&bias0[n];
#pragma unroll
            for (int j = 0; j < 4; ++j) {
                const int m = mb + j * 16;
                *(float4*)&((float*)C0)[(long)m * ldc + n] = make_float4(
                    acc[i][j][0] + b4.x, acc[i][j][1] + b4.y,
                    acc[i][j][2] + b4.z, acc[i][j][3] + b4.w);
            }
        } else { // MODE 3: whole block lives in one section (bn-uniform)
            const int sec = n >> 9, nn = n & 511;
            const float* bp = sec == 0 ? bias0 : (sec == 1 ? bias1 : bias2);
            const float4 b4 = *(const float4*)&bp[nn];
#pragma unroll
            for (int j = 0; j < 4; ++j) {
                const int m = mb + j * 16;
                if (sec < 2) {
                    uint16_t* Cq = (uint16_t*)(sec == 0 ? C0 : C1);
                    const uint32_t lo = (uint32_t)f2bf(acc[i][j][0] + b4.x) |
                                        ((uint32_t)f2bf(acc[i][j][1] + b4.y) << 16);
                    const uint32_t hi = (uint32_t)f2bf(acc[i][j][2] + b4.z) |
                                        ((uint32_t)f2bf(acc[i][j][3] + b4.w) << 16);
                    *(uint2*)&Cq[(long)m * 512 + nn] = make_uint2(lo, hi);
                } else { // V transposed: Vt[b][d][s], d = nn+r, s = m
                    const int bb = m >> 11, ss = m & 2047;
                    uint16_t* vt = (uint16_t*)C2 + ((long)bb * 512 + nn) * 2048 + ss;
                    vt[0]        = f2bf(acc[i][j][0] + b4.x);
                    vt[2048]     = f2bf(acc[i][j][1] + b4.y);
                    vt[2 * 2048] = f2bf(acc[i][j][2] + b4.z);
                    vt[3 * 2048] = f2bf(acc[i][j][3] + b4.w);
                }
            }
        }
    }
}

// x + pos_table -> bf16, 8 elems/thread, exact grid (4096 blocks)
__global__ __launch_bounds__(256) void prep_x(const float* __restrict__ x,
                                              const float* __restrict__ pos,
                                              uint16_t* __restrict__ xb)
{
    const long i8 = ((long)blockIdx.x * 256 + threadIdx.x) * 8;
    const long p8 = i8 & ((1l << 20) - 1);   // S*D = 2^20
    const float4* xv = (const float4*)(x + i8);
    const float4* pv = (const float4*)(pos + p8);
    const float4 a0 = xv[0], a1 = xv[1];
    const float4 b0 = pv[0], b1 = pv[1];
    uint16_t o[8];
    o[0] = f2bf(a0.x + b0.x); o[1] = f2bf(a0.y + b0.y);
    o[2] = f2bf(a0.z + b0.z); o[3] = f2bf(a0.w + b0.w);
    o[4] = f2bf(a1.x + b1.x); o[5] = f2bf(a1.y + b1.y);
    o[6] = f2bf(a1.z + b1.z); o[7] = f2bf(a1.w + b1.w);
    *(uint4*)(xb + i8) = *(uint4*)o;
}

// Wq,Wk,Wv -> stacked wqkv[1536,512] bf16; Wd -> wd bf16. 512 blocks exact.
__global__ __launch_bounds__(256) void prep_w(
    const float* __restrict__ Wq, const float* __restrict__ Wk,
    const float* __restrict__ Wv, const float* __restrict__ Wd,
    uint16_t* __restrict__ wqkv, uint16_t* __restrict__ wd)
{
    const long f = ((long)blockIdx.x * 256 + threadIdx.x) * 8;
    const int  w = (int)(f >> 18);          // 262144 elems per weight
    const long off = f & 262143;
    const float* src = (w == 0) ? Wq : (w == 1) ? Wk : (w == 2) ? Wv : Wd;
    uint16_t* dst = (w < 3) ? (wqkv + (long)w * 262144 + off) : (wd + off);
    const float4* s4 = (const float4*)(src + off);
    const float4 a = s4[0], b = s4[1];
    uint16_t o[8];
    o[0] = f2bf(a.x); o[1] = f2bf(a.y); o[2] = f2bf(a.z); o[3] = f2bf(a.w);
    o[4] = f2bf(b.x); o[5] = f2bf(b.y); o[6] = f2bf(b.z); o[7] = f2bf(b.w);
    *(uint4*)dst = *(uint4*)o;
}

// in-place row softmax over bf16 P rows of length 2048; 1 block (256 thr)/row
__global__ __launch_bounds__(256) void softmax_rows(uint16_t* __restrict__ P)
{
    uint16_t* p = P + (long)blockIdx.x * 2048;
    const int t = threadIdx.x;
    const int lane = t & 63, wave = t >> 6;

    uint4 raw = *(const uint4*)(p + t * 8);
    uint32_t u[4] = {raw.x, raw.y, raw.z, raw.w};
    float x[8];
#pragma unroll
    for (int i = 0; i < 4; ++i) {
        x[2 * i]     = __builtin_bit_cast(float, u[i] << 16);
        x[2 * i + 1] = __builtin_bit_cast(float, u[i] & 0xFFFF0000u);
    }
    float mx = x[0];
#pragma unroll
    for (int i = 1; i < 8; ++i) mx = fmaxf(mx, x[i]);
#pragma unroll
    for (int off = 32; off; off >>= 1) mx = fmaxf(mx, __shfl_xor(mx, off));
    __shared__ float sm[4], ss[4];
    if (lane == 0) sm[wave] = mx;
    __syncthreads();
    mx = fmaxf(fmaxf(sm[0], sm[1]), fmaxf(sm[2], sm[3]));

    float sum = 0.f;
#pragma unroll
    for (int i = 0; i < 8; ++i) { x[i] = __expf(x[i] - mx); sum += x[i]; }
#pragma unroll
    for (int off = 32; off; off >>= 1) sum += __shfl_xor(sum, off);
    if (lane == 0) ss[wave] = sum;
    __syncthreads();
    const float inv = 1.f / (ss[0] + ss[1] + ss[2] + ss[3]);

#pragma unroll
    for (int i = 0; i < 4; ++i) {
        const uint32_t lo = f2bf(x[2 * i] * inv);
        const uint32_t hi = f2bf(x[2 * i + 1] * inv);
        u[i] = lo | (hi << 16);
    }
    *(uint4*)(p + t * 8) = make_uint4(u[0], u[1], u[2], u[3]);
}

extern "C" void kernel_launch(void* const* d_in, const int* in_sizes, int n_in,
                              void* d_out, int out_size, void* d_ws, size_t ws_size,
                              hipStream_t stream)
{
    const float* x   = (const float*)d_in[0];
    const float* pos = (const float*)d_in[1];
    const float* Wq  = (const float*)d_in[2];
    const float* bq  = (const float*)d_in[3];
    const float* Wk  = (const float*)d_in[4];
    const float* bk  = (const float*)d_in[5];
    const float* Wv  = (const float*)d_in[6];
    const float* bv  = (const float*)d_in[7];
    const float* Wd  = (const float*)d_in[8];
    const float* bd  = (const float*)d_in[9];
    float* out = (float*)d_out;

    // workspace layout (bytes), total 153,092,096
    char* ws = (char*)d_ws;
    uint16_t* xb   = (uint16_t*)(ws);                 // 16,777,216  [16384,512]
    uint16_t* wqkv = (uint16_t*)(ws + 16777216);      //  1,572,864  [1536,512]
    uint16_t* wd   = (uint16_t*)(ws + 18350080);      //    524,288  [512,512]
    uint16_t* Qb   = (uint16_t*)(ws + 18874368);      // 16,777,216  [16384,512]
    uint16_t* Kb   = (uint16_t*)(ws + 35651584);      // 16,777,216  [16384,512]
    uint16_t* Vt   = (uint16_t*)(ws + 52428800);      // 16,777,216  [8,512,2048]
    uint16_t* Pb   = (uint16_t*)(ws + 69206016);      // 67,108,864  [8,2048,2048]
    uint16_t* yb   = (uint16_t*)(ws + 136314880);     // 16,777,216  [16384,512]

    prep_x<<<4096, 256, 0, stream>>>(x, pos, xb);
    prep_w<<<512, 256, 0, stream>>>(Wq, Wk, Wv, Wd, wqkv, wd);

    // Q|K|Vt = xb @ wqkv^T (+bias):  M=16384, N=1536, K=512
    // gm=128, gn=12 -> scols=3, stPerBatch=32*3=96, blocks=1536
    gemm_nt<3><<<1536, 256, 0, stream>>>(
        xb, wqkv, Qb, Kb, Vt, bq, bk, bv, 1.0f, 512, 512, 0, 0, 0, 3, 96);

    // P[b] = (Q[b] @ K[b]^T) * scale:  8 x [2048,2048], K=512
    // per batch gm=16, gn=16 -> scols=4, stPerBatch=16, blocks=2048
    gemm_nt<0><<<2048, 256, 0, stream>>>(
        Qb, Kb, Pb, nullptr, nullptr, nullptr, nullptr, nullptr,
        QK_SCALE, 512, 2048, (long)2048 * 512, (long)2048 * 512,
        (long)2048 * 2048, 4, 16);

    softmax_rows<<<16384, 256, 0, stream>>>(Pb);

    // y[b] = P[b] @ Vt[b]^T:  8 x [2048,512], K=2048
    // per batch gm=16, gn=4 -> scols=1, stPerBatch=4, blocks=512
    gemm_nt<0><<<512, 256, 0, stream>>>(
        Pb, Vt, yb, nullptr, nullptr, nullptr, nullptr, nullptr,
        1.0f, 2048, 512, (long)2048 * 2048, (long)512 * 2048,
        (long)2048 * 512, 1, 4);

    // out = y @ wd^T + bd:  M=16384, N=512, K=512, fp32 out
    // gm=128, gn=4 -> scols=1, stPerBatch=32, blocks=512
    gemm_nt<2><<<512, 256, 0, stream>>>(
        yb, wd, out, nullptr, nullptr, bd, nullptr, nullptr,
        1.0f, 512, 512, 0, 0, 0, 1, 32);
}